// Round 3
// baseline (80.102 us; speedup 1.0000x reference)
//
#include <hip/hip_runtime.h>
#include <math.h>

#define N 8192
#define BS 256
#define NCHUNK 4
#define CHUNK (N / NCHUNK)          // 2048 j's per block
#define NBLK ((N / 32) * NCHUNK)    // 1024 blocks
#define EPSV 1e-8f

// Persistent device-global counters. Each graph replay adds EXACTLY 32 to each
// sub-counter and 32 to the master, so (old & 31)==31 detects "last" on every
// replay without needing re-zeroing (workspace is poisoned, can't hold a counter).
__device__ unsigned cox_sub_ctr[32];
__device__ unsigned cox_master_ctr;

// Single dispatch. Phase 1 is byte-identical to the verified 66.06us kernel:
// 1024 blocks (256 i-groups x 4 j-chunks), 16 KB LDS -> 4 blocks/CU, all 1024
// blocks co-resident. Each block writes partial risk-set sums Spart[chunk][i].
// Then a two-level atomic-counter protocol elects the LAST block as finisher,
// which (after an agent-scope acquire fence) combines the partials, applies
// log + event mask, and writes the scalar loss. No second dispatch, no
// cooperative launch, no same-address atomic pileup (max 32 per address).
__global__ __launch_bounds__(BS) void cox_onepass(const float* __restrict__ risk,
                                                  const float* __restrict__ t,
                                                  const float* __restrict__ e,
                                                  float* __restrict__ Spart,
                                                  float* __restrict__ out) {
    __shared__ float sT[CHUNK];
    __shared__ float sE[CHUNK];
    __shared__ int sLast;

    const int tid = threadIdx.x;
    const int bid = blockIdx.x;
    const int chunk = bid & (NCHUNK - 1);
    const int iblk = bid >> 2;

    // ---- stage this chunk's t and exp(risk) into LDS, float4-vectorized ----
    const float4* t4g = (const float4*)t;
    const float4* r4g = (const float4*)risk;
    float4* sT4 = (float4*)sT;
    float4* sE4 = (float4*)sE;
    #pragma unroll
    for (int s = 0; s < CHUNK / 4 / BS; ++s) {   // 2 iterations
        int fl = tid + s * BS;
        int fg = chunk * (CHUNK / 4) + fl;
        float4 tv = t4g[fg];
        float4 rv = r4g[fg];
        sT4[fl] = tv;
        float4 ev;
        ev.x = __expf(rv.x);
        ev.y = __expf(rv.y);
        ev.z = __expf(rv.z);
        ev.w = __expf(rv.w);
        sE4[fl] = ev;
    }

    const int lane = tid & 63;
    const int wave = tid >> 6;
    const int i0 = iblk * 32 + wave * 8;         // this wave's 8 i's

    float ti[8];
    #pragma unroll
    for (int m = 0; m < 8; ++m) ti[m] = t[i0 + m];

    float sum[8];
    #pragma unroll
    for (int m = 0; m < 8; ++m) sum[m] = 0.0f;

    __syncthreads();

    // ---- main loop: 8 float4-iterations per lane covers the 2048-j chunk ----
    #pragma unroll
    for (int k = 0; k < CHUNK / 4 / 64; ++k) {   // 8 iterations, fully unrolled
        int f = lane + (k << 6);
        float4 tj = sT4[f];
        float4 ej = sE4[f];
        #pragma unroll
        for (int m = 0; m < 8; ++m) {
            float s0 = (tj.x >= ti[m]) ? ej.x : 0.0f;
            float s1 = (tj.y >= ti[m]) ? ej.y : 0.0f;
            float s2 = (tj.z >= ti[m]) ? ej.z : 0.0f;
            float s3 = (tj.w >= ti[m]) ? ej.w : 0.0f;
            sum[m] += (s0 + s1) + (s2 + s3);
        }
    }

    // ---- reduce each of the 8 sums across the 64 lanes ----
    float myS = 0.0f;
    #pragma unroll
    for (int m = 0; m < 8; ++m) {
        float v = sum[m];
        v += __shfl_xor(v, 32);
        v += __shfl_xor(v, 16);
        v += __shfl_xor(v, 8);
        v += __shfl_xor(v, 4);
        v += __shfl_xor(v, 2);
        v += __shfl_xor(v, 1);
        if (lane == m) myS = v;   // lane m keeps partial S for i = i0+m
    }
    if (lane < 8) {
        Spart[chunk * N + i0 + lane] = myS;
    }

    // ---- completion protocol: elect last block ----
    // __syncthreads lowers to s_waitcnt vmcnt(0) + s_barrier, so every wave's
    // Spart stores have retired to L2 before tid 0 proceeds.
    __syncthreads();
    if (tid == 0) {
        int last = 0;
        __threadfence();   // agent-scope release: write back L2 for other XCDs
        unsigned o = atomicAdd(&cox_sub_ctr[bid & 31], 1u);   // device-scope
        if ((o & 31u) == 31u) {
            // last arriver of this 32-block subgroup; propagate to master.
            __threadfence();   // acquire subgroup's writes, release onward
            unsigned m = atomicAdd(&cox_master_ctr, 1u);
            if ((m & 31u) == 31u) last = 1;    // last subgroup overall
        }
        sLast = last;
    }
    __syncthreads();
    if (!sLast) return;

    // ---- finisher: this block saw all 1024 counter increments ----
    __threadfence();   // agent-scope acquire: invalidate local L2, fresh Spart

    const float4* S0 = (const float4*)(Spart);
    const float4* S1 = (const float4*)(Spart + N);
    const float4* S2 = (const float4*)(Spart + 2 * N);
    const float4* S3 = (const float4*)(Spart + 3 * N);
    const float4* e4 = (const float4*)e;

    float acc = 0.0f;
    #pragma unroll
    for (int r = 0; r < N / 4 / BS; ++r) {   // 8 iterations, float4 per thread
        int f = tid + r * BS;
        float4 a = S0[f], b = S1[f], c = S2[f], d = S3[f];
        float4 rv = r4g[f], ev = e4[f];
        float Sx = (a.x + b.x) + (c.x + d.x);
        float Sy = (a.y + b.y) + (c.y + d.y);
        float Sz = (a.z + b.z) + (c.z + d.z);
        float Sw = (a.w + b.w) + (c.w + d.w);
        acc += ev.x * (rv.x - __logf(Sx + EPSV));
        acc += ev.y * (rv.y - __logf(Sy + EPSV));
        acc += ev.z * (rv.z - __logf(Sz + EPSV));
        acc += ev.w * (rv.w - __logf(Sw + EPSV));
    }

    acc += __shfl_xor(acc, 32);
    acc += __shfl_xor(acc, 16);
    acc += __shfl_xor(acc, 8);
    acc += __shfl_xor(acc, 4);
    acc += __shfl_xor(acc, 2);
    acc += __shfl_xor(acc, 1);

    __shared__ float sW[4];
    if (lane == 0) sW[wave] = acc;
    __syncthreads();
    if (tid == 0) {
        out[0] = -((sW[0] + sW[1]) + (sW[2] + sW[3])) * (1.0f / (float)N);
    }
}

extern "C" void kernel_launch(void* const* d_in, const int* in_sizes, int n_in,
                              void* d_out, int out_size, void* d_ws, size_t ws_size,
                              hipStream_t stream) {
    const float* risk = (const float*)d_in[0];
    const float* t    = (const float*)d_in[1];
    const float* e    = (const float*)d_in[2];
    float* out  = (float*)d_out;
    float* part = (float*)d_ws;   // NCHUNK * N floats = 128 KB of scratch

    cox_onepass<<<dim3(NBLK), dim3(BS), 0, stream>>>(risk, t, e, part, out);
}

// Round 4
// 66.716 us; speedup vs baseline: 1.2006x; 1.2006x over previous
//
#include <hip/hip_runtime.h>
#include <math.h>

#define N 8192
#define BS 256
#define NCHUNK 4
#define CHUNK (N / NCHUNK)        // 2048 j's per block
#define EPSV 1e-8f

// Kernel 1: grid (256 i-blocks, 4 j-chunks). Each block stages its chunk's
// t[] and exp(risk[]) into LDS (16 KB -> 4+ blocks/CU, 16 waves/CU), handles
// 32 i's; each wave owns 8 i's in registers, lanes slice the chunk's j's.
// Writes partial risk-set sums Spart[chunk][i] to workspace.
// NOTE (session journal): verified best at 66.06 us. Falsified alternatives:
//  - cooperative single-kernel: breaks graph capture (round 1, absmax=loss)
//  - all-j 64KB-LDS single kernel: 1 wave/SIMD occupancy collapse, +3.7 us
//  - last-block finisher w/ threadfence: agent-scope L2 wb/inv cost, +14 us
__global__ __launch_bounds__(BS) void cox_partial(const float* __restrict__ risk,
                                                  const float* __restrict__ t,
                                                  float* __restrict__ Spart) {
    __shared__ float sT[CHUNK];
    __shared__ float sE[CHUNK];

    const int tid = threadIdx.x;
    const int chunk = blockIdx.y;

    // ---- stage this chunk's t and exp(risk) into LDS, float4-vectorized ----
    const float4* t4g = (const float4*)t;
    const float4* r4g = (const float4*)risk;
    float4* sT4 = (float4*)sT;
    float4* sE4 = (float4*)sE;
    #pragma unroll
    for (int s = 0; s < CHUNK / 4 / BS; ++s) {   // 2 iterations
        int fl = tid + s * BS;                   // local float4 index
        int fg = chunk * (CHUNK / 4) + fl;       // global float4 index
        float4 tv = t4g[fg];
        float4 rv = r4g[fg];
        sT4[fl] = tv;
        float4 ev;
        ev.x = __expf(rv.x);
        ev.y = __expf(rv.y);
        ev.z = __expf(rv.z);
        ev.w = __expf(rv.w);
        sE4[fl] = ev;
    }

    const int lane = tid & 63;
    const int wave = tid >> 6;
    const int i0 = blockIdx.x * 32 + wave * 8;   // this wave's 8 i's

    // t_i values from global (uniform address across lanes -> L1 broadcast)
    float ti[8];
    #pragma unroll
    for (int m = 0; m < 8; ++m) ti[m] = t[i0 + m];

    float sum[8];
    #pragma unroll
    for (int m = 0; m < 8; ++m) sum[m] = 0.0f;

    __syncthreads();

    // ---- main loop: 8 float4-iterations per lane covers the 2048-j chunk ----
    #pragma unroll
    for (int k = 0; k < CHUNK / 4 / 64; ++k) {   // 8 iterations, fully unrolled
        int f = lane + (k << 6);
        float4 tj = sT4[f];
        float4 ej = sE4[f];
        #pragma unroll
        for (int m = 0; m < 8; ++m) {
            float s0 = (tj.x >= ti[m]) ? ej.x : 0.0f;
            float s1 = (tj.y >= ti[m]) ? ej.y : 0.0f;
            float s2 = (tj.z >= ti[m]) ? ej.z : 0.0f;
            float s3 = (tj.w >= ti[m]) ? ej.w : 0.0f;
            sum[m] += (s0 + s1) + (s2 + s3);
        }
    }

    // ---- reduce each of the 8 sums across the 64 lanes ----
    float myS = 0.0f;
    #pragma unroll
    for (int m = 0; m < 8; ++m) {
        float v = sum[m];
        v += __shfl_xor(v, 32);
        v += __shfl_xor(v, 16);
        v += __shfl_xor(v, 8);
        v += __shfl_xor(v, 4);
        v += __shfl_xor(v, 2);
        v += __shfl_xor(v, 1);
        if (lane == m) myS = v;   // lane m keeps partial S for i = i0+m
    }

    if (lane < 8) {
        Spart[chunk * N + i0 + lane] = myS;
    }
}

// Kernel 2: one 1024-thread block. Combine the 4 chunk partials per i, apply
// log + event mask, reduce 8192 contributions to the scalar loss.
__global__ __launch_bounds__(1024) void cox_final(const float* __restrict__ Spart,
                                                  const float* __restrict__ risk,
                                                  const float* __restrict__ e,
                                                  float* __restrict__ out) {
    const int tid = threadIdx.x;
    const int lane = tid & 63;
    const int wave = tid >> 6;

    float acc = 0.0f;
    #pragma unroll
    for (int r = 0; r < N / 1024; ++r) {   // 8 iterations
        int i = tid + r * 1024;
        float S = Spart[i] + Spart[N + i] + Spart[2 * N + i] + Spart[3 * N + i];
        acc += e[i] * (risk[i] - __logf(S + EPSV));
    }

    acc += __shfl_xor(acc, 32);
    acc += __shfl_xor(acc, 16);
    acc += __shfl_xor(acc, 8);
    acc += __shfl_xor(acc, 4);
    acc += __shfl_xor(acc, 2);
    acc += __shfl_xor(acc, 1);

    __shared__ float sW[16];
    if (lane == 0) sW[wave] = acc;
    __syncthreads();
    if (tid == 0) {
        float tot = 0.0f;
        #pragma unroll
        for (int x = 0; x < 16; ++x) tot += sW[x];
        out[0] = -tot * (1.0f / (float)N);
    }
}

extern "C" void kernel_launch(void* const* d_in, const int* in_sizes, int n_in,
                              void* d_out, int out_size, void* d_ws, size_t ws_size,
                              hipStream_t stream) {
    const float* risk = (const float*)d_in[0];
    const float* t    = (const float*)d_in[1];
    const float* e    = (const float*)d_in[2];
    float* out  = (float*)d_out;
    float* part = (float*)d_ws;   // NCHUNK * N floats = 128 KB of scratch

    dim3 grid(N / 32, NCHUNK);
    cox_partial<<<grid, BS, 0, stream>>>(risk, t, part);
    cox_final<<<1, 1024, 0, stream>>>(part, risk, e, out);
}